// Round 2
// baseline (1706.619 us; speedup 1.0000x reference)
//
#include <hip/hip_runtime.h>

// Problem constants (fixed by setup_inputs)
constexpr int Bb = 8, Nn = 1024, Cc = 768, Hh = 12, Dd = 64;
constexpr int Mtot = Bb * Nn;          // 8192
constexpr int QKVN = 3 * Cc;           // 2304
constexpr int BH = Bb * Hh;            // 96

// ---------------------------------------------------------------------------
// Kernel 1: QKV GEMM  x[8192,768] @ w_qkv[768,2304] -> q/k/v [96][1024][64]
// 128x128 tile, BK=16, 256 threads, 8x8 microtile.
// ---------------------------------------------------------------------------
__global__ __launch_bounds__(256)
void gemm_qkv(const float* __restrict__ A, const float* __restrict__ Bw,
              float* __restrict__ qkv_ws) {
  constexpr int BM = 128, BN = 128, BK = 16;
  __shared__ float As[BK][BM + 4];   // transposed A tile, +4 pad keeps f4 alignment
  __shared__ float Bs[BK][BN];

  const int bn = blockIdx.x;          // 0..17
  const int bm = blockIdx.y;          // 0..63
  const int tid = threadIdx.x;
  const int tr = tid >> 4;            // 0..15
  const int tc = tid & 15;            // 0..15
  const int m0 = bm * BM, n0 = bn * BN;

  float acc[8][8] = {};

  for (int k0 = 0; k0 < Cc; k0 += BK) {
    // A tile 128x16 -> As[k][m] (transposed store)
    #pragma unroll
    for (int s = 0; s < 2; ++s) {
      int f4 = tid + s * 256;              // 0..511
      int row = f4 >> 2;                   // 0..127
      int c4 = (f4 & 3) * 4;               // 0,4,8,12
      float4 av = *(const float4*)&A[(size_t)(m0 + row) * Cc + k0 + c4];
      As[c4 + 0][row] = av.x;
      As[c4 + 1][row] = av.y;
      As[c4 + 2][row] = av.z;
      As[c4 + 3][row] = av.w;
    }
    // B tile 16x128
    #pragma unroll
    for (int s = 0; s < 2; ++s) {
      int f4 = tid + s * 256;
      int row = f4 >> 5;                   // 0..15
      int c4 = (f4 & 31) * 4;              // 0..124
      *(float4*)&Bs[row][c4] =
          *(const float4*)&Bw[(size_t)(k0 + row) * QKVN + n0 + c4];
    }
    __syncthreads();

    #pragma unroll
    for (int k = 0; k < BK; ++k) {
      float a[8], bb[8];
      *(float4*)&a[0] = *(const float4*)&As[k][tr * 8];
      *(float4*)&a[4] = *(const float4*)&As[k][tr * 8 + 4];
      *(float4*)&bb[0] = *(const float4*)&Bs[k][tc * 8];
      *(float4*)&bb[4] = *(const float4*)&Bs[k][tc * 8 + 4];
      #pragma unroll
      for (int i = 0; i < 8; ++i)
        #pragma unroll
        for (int j = 0; j < 8; ++j)
          acc[i][j] = fmaf(a[i], bb[j], acc[i][j]);
    }
    __syncthreads();
  }

  // Scatter epilogue: e = t*768 + h*64 + d ; dst [t][b*12+h][n][d]
  const int t = n0 / Cc;                   // uniform per block (768 % 128 == 0)
  #pragma unroll
  for (int i = 0; i < 8; ++i) {
    int m = m0 + tr * 8 + i;
    int bIdx = m >> 10;
    int nIdx = m & 1023;
    #pragma unroll
    for (int j = 0; j < 8; ++j) {
      int e = n0 + tc * 8 + j;
      int rem = e - t * Cc;
      int h = rem >> 6;
      int d = rem & 63;
      qkv_ws[(((size_t)t * BH + bIdx * Hh + h) * Nn + nIdx) * Dd + d] = acc[i][j];
    }
  }
}

// ---------------------------------------------------------------------------
// Kernel 2: attention. 1 wave per block; each lane owns one query row.
// q[64], o[64] in registers; online softmax lane-local; K/V rows read via
// wave-uniform pointers (scalarizable to s_load).
// ---------------------------------------------------------------------------
__global__ __launch_bounds__(64)
void attn(const float* __restrict__ qkv_ws, float* __restrict__ aout) {
  const int blk = blockIdx.x;           // 0..1535
  const int bh = blk >> 4;              // 16 waves per (b,h)
  const int rt = blk & 15;
  const int lane = threadIdx.x;         // 0..63
  const int row = rt * 64 + lane;
  const int b = bh / Hh, h = bh % Hh;

  const float* qp = qkv_ws + ((size_t)bh * Nn + row) * Dd;
  const float4* kbase = (const float4*)(qkv_ws + ((size_t)(BH + bh) * Nn) * Dd);
  const float4* vbase = (const float4*)(qkv_ws + ((size_t)(2 * BH + bh) * Nn) * Dd);

  float q[64];
  #pragma unroll
  for (int d4 = 0; d4 < 16; ++d4) {
    float4 t4 = ((const float4*)qp)[d4];
    q[d4 * 4 + 0] = t4.x; q[d4 * 4 + 1] = t4.y;
    q[d4 * 4 + 2] = t4.z; q[d4 * 4 + 3] = t4.w;
  }

  float o[64] = {};
  float mrun = -1e30f, l = 0.f;
  const float scale = 0.125f;           // 64^-0.5

  for (int jt = 0; jt < Nn; jt += 8) {
    float s[8];
    #pragma unroll
    for (int jj = 0; jj < 8; ++jj) {
      const float4* kr = kbase + (size_t)(jt + jj) * 16;
      float acc = 0.f;
      #pragma unroll
      for (int d4 = 0; d4 < 16; ++d4) {
        float4 kv = kr[d4];
        acc = fmaf(q[d4 * 4 + 0], kv.x, acc);
        acc = fmaf(q[d4 * 4 + 1], kv.y, acc);
        acc = fmaf(q[d4 * 4 + 2], kv.z, acc);
        acc = fmaf(q[d4 * 4 + 3], kv.w, acc);
      }
      s[jj] = acc * scale;
    }
    float tmax = s[0];
    #pragma unroll
    for (int jj = 1; jj < 8; ++jj) tmax = fmaxf(tmax, s[jj]);
    float mn = fmaxf(mrun, tmax);
    float corr = __expf(mrun - mn);
    l *= corr;
    #pragma unroll
    for (int d = 0; d < 64; ++d) o[d] *= corr;
    #pragma unroll
    for (int jj = 0; jj < 8; ++jj) {
      float p = __expf(s[jj] - mn);
      l += p;
      const float4* vr = vbase + (size_t)(jt + jj) * 16;
      #pragma unroll
      for (int d4 = 0; d4 < 16; ++d4) {
        float4 vv = vr[d4];
        o[d4 * 4 + 0] = fmaf(p, vv.x, o[d4 * 4 + 0]);
        o[d4 * 4 + 1] = fmaf(p, vv.y, o[d4 * 4 + 1]);
        o[d4 * 4 + 2] = fmaf(p, vv.z, o[d4 * 4 + 2]);
        o[d4 * 4 + 3] = fmaf(p, vv.w, o[d4 * 4 + 3]);
      }
    }
    mrun = mn;
  }

  const float inv = 1.0f / l;
  float* op = aout + ((size_t)(b * Nn + row)) * Cc + h * Dd;
  #pragma unroll
  for (int d4 = 0; d4 < 16; ++d4) {
    float4 r;
    r.x = o[d4 * 4 + 0] * inv; r.y = o[d4 * 4 + 1] * inv;
    r.z = o[d4 * 4 + 2] * inv; r.w = o[d4 * 4 + 3] * inv;
    *(float4*)&op[d4 * 4] = r;
  }
}

// ---------------------------------------------------------------------------
// Kernel 3: proj GEMM  aout[8192,768] @ w_proj[768,768] + b_proj -> out
// ---------------------------------------------------------------------------
__global__ __launch_bounds__(256)
void gemm_proj(const float* __restrict__ A, const float* __restrict__ Bw,
               const float* __restrict__ bias, float* __restrict__ out) {
  constexpr int BM = 128, BN = 128, BK = 16;
  __shared__ float As[BK][BM + 4];
  __shared__ float Bs[BK][BN];

  const int bn = blockIdx.x;           // 0..5
  const int bm = blockIdx.y;           // 0..63
  const int tid = threadIdx.x;
  const int tr = tid >> 4, tc = tid & 15;
  const int m0 = bm * BM, n0 = bn * BN;

  float acc[8][8] = {};

  for (int k0 = 0; k0 < Cc; k0 += BK) {
    #pragma unroll
    for (int s = 0; s < 2; ++s) {
      int f4 = tid + s * 256;
      int row = f4 >> 2;
      int c4 = (f4 & 3) * 4;
      float4 av = *(const float4*)&A[(size_t)(m0 + row) * Cc + k0 + c4];
      As[c4 + 0][row] = av.x;
      As[c4 + 1][row] = av.y;
      As[c4 + 2][row] = av.z;
      As[c4 + 3][row] = av.w;
    }
    #pragma unroll
    for (int s = 0; s < 2; ++s) {
      int f4 = tid + s * 256;
      int row = f4 >> 5;
      int c4 = (f4 & 31) * 4;
      *(float4*)&Bs[row][c4] =
          *(const float4*)&Bw[(size_t)(k0 + row) * Cc + n0 + c4];
    }
    __syncthreads();

    #pragma unroll
    for (int k = 0; k < BK; ++k) {
      float a[8], bb[8];
      *(float4*)&a[0] = *(const float4*)&As[k][tr * 8];
      *(float4*)&a[4] = *(const float4*)&As[k][tr * 8 + 4];
      *(float4*)&bb[0] = *(const float4*)&Bs[k][tc * 8];
      *(float4*)&bb[4] = *(const float4*)&Bs[k][tc * 8 + 4];
      #pragma unroll
      for (int i = 0; i < 8; ++i)
        #pragma unroll
        for (int j = 0; j < 8; ++j)
          acc[i][j] = fmaf(a[i], bb[j], acc[i][j]);
    }
    __syncthreads();
  }

  float bv[8];
  #pragma unroll
  for (int j = 0; j < 8; ++j) bv[j] = bias[n0 + tc * 8 + j];

  #pragma unroll
  for (int i = 0; i < 8; ++i) {
    int m = m0 + tr * 8 + i;
    float4 r0, r1;
    r0.x = acc[i][0] + bv[0]; r0.y = acc[i][1] + bv[1];
    r0.z = acc[i][2] + bv[2]; r0.w = acc[i][3] + bv[3];
    r1.x = acc[i][4] + bv[4]; r1.y = acc[i][5] + bv[5];
    r1.z = acc[i][6] + bv[6]; r1.w = acc[i][7] + bv[7];
    *(float4*)&out[(size_t)m * Cc + n0 + tc * 8] = r0;
    *(float4*)&out[(size_t)m * Cc + n0 + tc * 8 + 4] = r1;
  }
}

// ---------------------------------------------------------------------------
extern "C" void kernel_launch(void* const* d_in, const int* in_sizes, int n_in,
                              void* d_out, int out_size, void* d_ws, size_t ws_size,
                              hipStream_t stream) {
  const float* x      = (const float*)d_in[0];
  const float* w_qkv  = (const float*)d_in[1];
  const float* w_proj = (const float*)d_in[2];
  const float* b_proj = (const float*)d_in[3];
  float* out = (float*)d_out;

  float* qkvws = (float*)d_ws;                               // 3*96*1024*64 f32
  float* aout  = qkvws + (size_t)3 * BH * Nn * Dd;           // 8192*768 f32

  dim3 g1(QKVN / 128, Mtot / 128);
  gemm_qkv<<<g1, 256, 0, stream>>>(x, w_qkv, qkvws);

  attn<<<BH * (Nn / 64), 64, 0, stream>>>(qkvws, aout);

  dim3 g3(Cc / 128, Mtot / 128);
  gemm_proj<<<g3, 256, 0, stream>>>(aout, w_proj, b_proj, out);
}